// Round 8
// baseline (297.034 us; speedup 1.0000x reference)
//
#include <hip/hip_runtime.h>
#include <math.h>

#define C_DIM 128
#define H_NUM 8
#define DH_NUM 16
#define HD 128   // H*DH
#define PC 32    // H*NP

typedef __attribute__((ext_vector_type(8))) short bf16x8;
typedef __attribute__((ext_vector_type(4))) float f32x4;
typedef __attribute__((ext_vector_type(4))) unsigned short u16x4;

// ---------------- helpers ----------------
__device__ __forceinline__ float dot4f(float4 a, float4 b){
  return a.x*b.x + a.y*b.y + a.z*b.z + a.w*b.w;
}
__device__ __forceinline__ float4 scale4(float4 a, float s){
  return make_float4(a.x*s, a.y*s, a.z*s, a.w*s);
}
__device__ __forceinline__ float4 fma4(float4 acc, float p, float4 v){
  return make_float4(acc.x + p*v.x, acc.y + p*v.y, acc.z + p*v.z, acc.w + p*v.w);
}
__device__ __forceinline__ float sqdiff4(float4 a, float4 b){
  float dx = a.x - b.x, dy = a.y - b.y, dz = a.z - b.z, dw = a.w - b.w;
  return dx*dx + dy*dy + dz*dz + dw*dw;
}
__device__ __forceinline__ float gelu_exact(float v){
  return 0.5f * v * (1.0f + erff(v * 0.70710678118654752440f));
}
__device__ __forceinline__ unsigned short f2bf(float f){
  unsigned u = __builtin_bit_cast(unsigned, f);
  u += 0x7FFF + ((u >> 16) & 1);           // RNE to bf16
  return (unsigned short)(u >> 16);
}
__device__ __forceinline__ void ldbf8(const unsigned short* p, float4& lo, float4& hi){
  uint4 u = *(const uint4*)p;
  lo.x = __uint_as_float(u.x << 16); lo.y = __uint_as_float(u.x & 0xffff0000u);
  lo.z = __uint_as_float(u.y << 16); lo.w = __uint_as_float(u.y & 0xffff0000u);
  hi.x = __uint_as_float(u.z << 16); hi.y = __uint_as_float(u.z & 0xffff0000u);
  hi.z = __uint_as_float(u.w << 16); hi.w = __uint_as_float(u.w & 0xffff0000u);
}
__device__ __forceinline__ float4 ldbf4(const unsigned short* p){
  uint2 u = *(const uint2*)p;
  return make_float4(__uint_as_float(u.x << 16), __uint_as_float(u.x & 0xffff0000u),
                     __uint_as_float(u.y << 16), __uint_as_float(u.y & 0xffff0000u));
}
// row-offset modes: 0 -> r*ld ; 1 -> x-like (N,4,C) vector rows
__device__ __forceinline__ size_t row_off(int mode, int r, int ld){
  if (mode == 0) return (size_t)r * (size_t)ld;
  int n3 = r / 3;
  int xd = r - n3 * 3;
  return (size_t)n3 * 512 + (size_t)(xd + 1) * 128;
}

#define RED4(v, off) { v.x += __shfl_xor(v.x, off); v.y += __shfl_xor(v.y, off); \
                       v.z += __shfl_xor(v.z, off); v.w += __shfl_xor(v.w, off); }

// ---------------- CSR build ----------------
__global__ void count_kernel(const int* __restrict__ ei, int* __restrict__ deg, int E){
  int e = blockIdx.x * blockDim.x + threadIdx.x;
  if (e < E) atomicAdd(&deg[ei[E + e]], 1);
}

__global__ __launch_bounds__(1024) void scan_kernel(const int* __restrict__ deg,
                                                    int* __restrict__ row_start, int n){
  __shared__ int sums[1024];
  int tid = threadIdx.x;
  int chunk = (n + 1023) >> 10;
  int beg = tid * chunk;
  int end = beg + chunk; if (end > n) end = n;
  int s = 0;
  for (int i = beg; i < end; ++i) s += deg[i];
  sums[tid] = s;
  __syncthreads();
  for (int off = 1; off < 1024; off <<= 1){
    int v = (tid >= off) ? sums[tid - off] : 0;
    __syncthreads();
    sums[tid] += v;
    __syncthreads();
  }
  int run = (tid > 0) ? sums[tid - 1] : 0;
  for (int i = beg; i < end; ++i){ row_start[i] = run; run += deg[i]; }
  if (tid == 1023) row_start[n] = sums[1023];
}

__global__ void fill_kernel(const int* __restrict__ ei, const int* __restrict__ row_start,
                            int* __restrict__ cursor, int* __restrict__ csr_src, int E){
  int e = blockIdx.x * blockDim.x + threadIdx.x;
  if (e >= E) return;
  int s = ei[e];
  int d = ei[E + e];
  int pos = atomicAdd(&cursor[d], 1);
  csr_src[row_start[d] + pos] = s;
}

// ------- pack ALL weights to bf16, transposed [N][K], concatenated -------
__global__ void pack_bf16_kernel(const float* __restrict__ Wq, const float* __restrict__ Wk,
    const float* __restrict__ Wv, const float* __restrict__ Wqp,
    const float* __restrict__ Wkp, const float* __restrict__ Wvp,
    const float* __restrict__ Wo_s, const float* __restrict__ Wo_pts,
    const float* __restrict__ W1, const float* __restrict__ W2,
    const float* __restrict__ Wl, unsigned short* __restrict__ out)
{
  int i = blockIdx.x * blockDim.x + threadIdx.x;
  float v;
  if (i < 49152){                       // Bqkv_t [384][128]
    int nn = i >> 7, k = i & 127;
    int sel = nn >> 7, nc = nn & 127;
    const float* W = (sel == 0) ? Wq : (sel == 1) ? Wk : Wv;
    v = W[k * 128 + nc];
  } else if (i < 61440){                // Bpts_t [96][128]
    int j = i - 49152;
    int nn = j >> 7, k = j & 127;
    int sel = nn >> 5, nc = nn & 31;
    const float* W = (sel == 0) ? Wqp : (sel == 1) ? Wkp : Wvp;
    v = W[k * 32 + nc];
  } else if (i < 77824){                // Wos_t [128][128]
    int j = i - 61440;
    int nn = j >> 7, k = j & 127;
    v = Wo_s[k * 128 + nn];
  } else if (i < 81920){                // Wop_t [128][32]
    int j = i - 77824;
    int nn = j >> 5, k = j & 31;
    v = Wo_pts[k * 128 + nn];
  } else if (i < 147456){               // W1_t [256][256]
    int j = i - 81920;
    int nn = j >> 8, k = j & 255;
    v = W1[k * 256 + nn];
  } else if (i < 212992){               // W2_t [256][256]
    int j = i - 147456;
    int nn = j >> 8, k = j & 255;
    v = W2[k * 256 + nn];
  } else {                              // Wl_t [128][128]
    int j = i - 212992;
    int nn = j >> 7, k = j & 127;
    v = Wl[k * 128 + nn];
  }
  out[i] = f2bf(v);
}

// ---------------- bf16 MFMA GEMM (used for the two projections) ----------
template<int BM, int BN, int BK>
__global__ __launch_bounds__(256) void mfma_gemm(
    const float* __restrict__ A, int amode, int lda,
    const unsigned short* __restrict__ Bt,
    unsigned short* __restrict__ Cbf, int ldc,
    const float* __restrict__ rowadd,
    int M, int K, int Nc, int epi)
{
  constexpr int LDSK = BK + 8;
  constexpr int MI = BM / 32, NI = BN / 32, KI = BK / 32;
  __shared__ alignas(16) unsigned short As[BM][LDSK];
  __shared__ alignas(16) unsigned short Bs[BN][LDSK];
  const int tid = threadIdx.x;
  const int wave = tid >> 6;
  const int lane = tid & 63;
  const int wr = wave >> 1;
  const int wc = wave & 1;
  const int l15 = lane & 15;
  const int l4  = lane >> 4;
  const int rb = blockIdx.x * BM;
  const int cb = blockIdx.y * BN;

  f32x4 acc[MI][NI];
  #pragma unroll
  for (int mi = 0; mi < MI; ++mi)
    #pragma unroll
    for (int ni = 0; ni < NI; ++ni)
      acc[mi][ni] = (f32x4){0.f, 0.f, 0.f, 0.f};

  for (int k0 = 0; k0 < K; k0 += BK){
    constexpr int RF4 = BK / 4;
    constexpr int AF4 = BM * RF4 / 256;
    #pragma unroll
    for (int i = 0; i < AF4; ++i){
      int fi = tid + i * 256;
      int r  = fi / RF4;
      int c4 = fi % RF4;
      int kg = k0 + c4 * 4;
      int row = rb + r;
      u16x4 pk = (u16x4){0, 0, 0, 0};
      if (row < M && kg < K){
        float4 v = *(const float4*)&A[row_off(amode, row, lda) + (size_t)kg];
        pk = (u16x4){f2bf(v.x), f2bf(v.y), f2bf(v.z), f2bf(v.w)};
      }
      *(u16x4*)&As[r][c4 * 4] = pk;
    }
    constexpr int RC8 = BK / 8;
    constexpr int BC8 = BN * RC8 / 256;
    #pragma unroll
    for (int i = 0; i < BC8; ++i){
      int fi = tid + i * 256;
      int r  = fi / RC8;
      int kc = (fi % RC8) * 8;
      int col = cb + r;
      int kg = k0 + kc;
      bf16x8 val = 0;
      if (col < Nc && kg < K) val = *(const bf16x8*)&Bt[(size_t)col * K + kg];
      *(bf16x8*)&Bs[r][kc] = val;
    }
    __syncthreads();
    #pragma unroll
    for (int kk = 0; kk < KI; ++kk){
      bf16x8 af[MI], bfr[NI];
      #pragma unroll
      for (int mi = 0; mi < MI; ++mi)
        af[mi] = *(const bf16x8*)&As[wr * (BM/2) + mi * 16 + l15][kk * 32 + l4 * 8];
      #pragma unroll
      for (int ni = 0; ni < NI; ++ni)
        bfr[ni] = *(const bf16x8*)&Bs[wc * (BN/2) + ni * 16 + l15][kk * 32 + l4 * 8];
      #pragma unroll
      for (int mi = 0; mi < MI; ++mi)
        #pragma unroll
        for (int ni = 0; ni < NI; ++ni)
          acc[mi][ni] = __builtin_amdgcn_mfma_f32_16x16x32_bf16(
              af[mi], bfr[ni], acc[mi][ni], 0, 0, 0);
    }
    __syncthreads();
  }

  #pragma unroll
  for (int mi = 0; mi < MI; ++mi){
    #pragma unroll
    for (int ni = 0; ni < NI; ++ni){
      int col = cb + wc * (BN/2) + ni * 16 + l15;
      if (col >= Nc) continue;
      #pragma unroll
      for (int r = 0; r < 4; ++r){
        int row = rb + wr * (BM/2) + mi * 16 + l4 * 4 + r;
        if (row >= M) continue;
        float val = acc[mi][ni][r];
        if (epi == 1) val += rowadd[row];
        Cbf[(size_t)row * ldc + col] = f2bf(val);
      }
    }
  }
}

// ---------------- per-node online-softmax attention over CSR (bf16 in) -----
// One wave per node: 8 edge-slots (g) x 8 heads (h); 2 edge-groups per iter.
__global__ __launch_bounds__(64) void attn_kernel(
    const unsigned short* __restrict__ qkv, const unsigned short* __restrict__ pts,
    const float* __restrict__ gamma,
    const int* __restrict__ row_start, const int* __restrict__ csr_src,
    float* __restrict__ agg_s, float* __restrict__ agg_p, int n)
{
  const int node = blockIdx.x;
  if (node >= n) return;
  const int lane = threadIdx.x;
  const int g = lane >> 3;
  const int h = lane & 7;

  float4 qa, qb, qc, qd;
  ldbf8(qkv + (size_t)node * 384 + h * 16, qa, qb);
  ldbf8(qkv + (size_t)node * 384 + h * 16 + 8, qc, qd);
  const float4 qp0 = ldbf4(pts + ((size_t)node * 3 + 0) * 96 + h * 4);
  const float4 qp1 = ldbf4(pts + ((size_t)node * 3 + 1) * 96 + h * 4);
  const float4 qp2 = ldbf4(pts + ((size_t)node * 3 + 2) * 96 + h * 4);
  const float c05 = 0.5f * log1pf(expf(gamma[h]));

  const int e0 = row_start[node], e1 = row_start[node + 1];

  float m_run = -INFINITY;
  float zacc = 0.f;
  float4 as0 = make_float4(0,0,0,0), as1 = as0, as2 = as0, as3 = as0;
  float4 ap0 = as0, ap1 = as0, ap2 = as0;

  for (int base = e0; base < e1; base += 16){
    const int ea = base + g;
    const int eb = base + 8 + g;
    const bool va = (ea < e1);
    const bool vb = (eb < e1);
    const int sa  = va ? csr_src[ea] : 0;
    const int sb_ = vb ? csr_src[eb] : 0;

    // ---- K + kp for both groups (loads issued together) ----
    float4 ka0, ka1, ka2, ka3, kb0, kb1, kb2, kb3;
    ldbf8(qkv + (size_t)sa  * 384 + 128 + h * 16,     ka0, ka1);
    ldbf8(qkv + (size_t)sa  * 384 + 128 + h * 16 + 8, ka2, ka3);
    ldbf8(qkv + (size_t)sb_ * 384 + 128 + h * 16,     kb0, kb1);
    ldbf8(qkv + (size_t)sb_ * 384 + 128 + h * 16 + 8, kb2, kb3);
    const float4 kpa0 = ldbf4(pts + ((size_t)sa  * 3 + 0) * 96 + 32 + h * 4);
    const float4 kpa1 = ldbf4(pts + ((size_t)sa  * 3 + 1) * 96 + 32 + h * 4);
    const float4 kpa2 = ldbf4(pts + ((size_t)sa  * 3 + 2) * 96 + 32 + h * 4);
    const float4 kpb0 = ldbf4(pts + ((size_t)sb_ * 3 + 0) * 96 + 32 + h * 4);
    const float4 kpb1 = ldbf4(pts + ((size_t)sb_ * 3 + 1) * 96 + 32 + h * 4);
    const float4 kpb2 = ldbf4(pts + ((size_t)sb_ * 3 + 2) * 96 + 32 + h * 4);

    float dota = dot4f(qa, ka0) + dot4f(qb, ka1) + dot4f(qc, ka2) + dot4f(qd, ka3);
    float dotb = dot4f(qa, kb0) + dot4f(qb, kb1) + dot4f(qc, kb2) + dot4f(qd, kb3);
    float pda = sqdiff4(qp0, kpa0) + sqdiff4(qp1, kpa1) + sqdiff4(qp2, kpa2);
    float pdb = sqdiff4(qp0, kpb0) + sqdiff4(qp1, kpb1) + sqdiff4(qp2, kpb2);
    float la = va ? (dota * 0.25f - c05 * pda) : -INFINITY;
    float lb = vb ? (dotb * 0.25f - c05 * pdb) : -INFINITY;

    // tile max over 16 edges (8 slots x 2 groups)
    float tmax = fmaxf(la, lb);
    tmax = fmaxf(tmax, __shfl_xor(tmax, 8));
    tmax = fmaxf(tmax, __shfl_xor(tmax, 16));
    tmax = fmaxf(tmax, __shfl_xor(tmax, 32));
    float m_new = fmaxf(m_run, tmax);
    float sc = expf(m_run - m_new);    // exp(-inf)=0 on first iter
    float pa = va ? expf(la - m_new) : 0.f;
    float pb = vb ? expf(lb - m_new) : 0.f;
    m_run = m_new;

    // ---- V + vp for both groups ----
    float4 va0, va1, va2, va3, vb0, vb1, vb2, vb3;
    ldbf8(qkv + (size_t)sa  * 384 + 256 + h * 16,     va0, va1);
    ldbf8(qkv + (size_t)sa  * 384 + 256 + h * 16 + 8, va2, va3);
    ldbf8(qkv + (size_t)sb_ * 384 + 256 + h * 16,     vb0, vb1);
    ldbf8(qkv + (size_t)sb_ * 384 + 256 + h * 16 + 8, vb2, vb3);
    const float4 vpa0 = ldbf4(pts + ((size_t)sa  * 3 + 0) * 96 + 64 + h * 4);
    const float4 vpa1 = ldbf4(pts + ((size_t)sa  * 3 + 1) * 96 + 64 + h * 4);
    const float4 vpa2 = ldbf4(pts + ((size_t)sa  * 3 + 2) * 96 + 64 + h * 4);
    const float4 vpb0 = ldbf4(pts + ((size_t)sb_ * 3 + 0) * 96 + 64 + h * 4);
    const float4 vpb1 = ldbf4(pts + ((size_t)sb_ * 3 + 1) * 96 + 64 + h * 4);
    const float4 vpb2 = ldbf4(pts + ((size_t)sb_ * 3 + 2) * 96 + 64 + h * 4);

    zacc = zacc * sc + pa + pb;
    as0 = fma4(fma4(scale4(as0, sc), pa, va0), pb, vb0);
    as1 = fma4(fma4(scale4(as1, sc), pa, va1), pb, vb1);
    as2 = fma4(fma4(scale4(as2, sc), pa, va2), pb, vb2);
    as3 = fma4(fma4(scale4(as3, sc), pa, va3), pb, vb3);
    ap0 = fma4(fma4(scale4(ap0, sc), pa, vpa0), pb, vpb0);
    ap1 = fma4(fma4(scale4(ap1, sc), pa, vpa1), pb, vpb1);
    ap2 = fma4(fma4(scale4(ap2, sc), pa, vpa2), pb, vpb2);
  }

  for (int off = 8; off < 64; off <<= 1){
    zacc += __shfl_xor(zacc, off);
    RED4(as0, off); RED4(as1, off); RED4(as2, off); RED4(as3, off);
    RED4(ap0, off); RED4(ap1, off); RED4(ap2, off);
  }
  float inv = 1.f / (zacc + 1e-9f);
  if (g == 0){
    float4* o = (float4*)(agg_s + (size_t)node * HD + h * DH_NUM);
    o[0] = scale4(as0, inv); o[1] = scale4(as1, inv);
    o[2] = scale4(as2, inv); o[3] = scale4(as3, inv);
    *(float4*)(agg_p + ((size_t)node * 3 + 0) * PC + h * 4) = scale4(ap0, inv);
    *(float4*)(agg_p + ((size_t)node * 3 + 1) * PC + h * 4) = scale4(ap1, inv);
    *(float4*)(agg_p + ((size_t)node * 3 + 2) * PC + h * 4) = scale4(ap2, inv);
  }
}

// ============ fused tail v2: 32 nodes/block ============
// A1: xmid_s = aggs@Wos + bo_s + x_s    -> out scalar rows
// A2: xmid_v = (aggp - t)@Wop + x_v     -> out vector rows
// B : x1 = [xmid_s | ||xmid_v||]        -> LDS A1 (bf16)
// C : h = gelu(x1@W1 + b1)              -> LDS A2 (bf16)
// D : y = h@W2 + b2; col<128: out_s += y ; col>=128: gate=sigmoid(y) -> YG
// E : out_v += (xmid_v@Wl) * gate
__global__ __launch_bounds__(256) void fused_tail_kernel(
    const float* __restrict__ aggs, const float* __restrict__ aggp,
    const float* __restrict__ t, const float* __restrict__ x,
    const unsigned short* __restrict__ Wos_t, const unsigned short* __restrict__ Wop_t,
    const unsigned short* __restrict__ W1_t, const unsigned short* __restrict__ W2_t,
    const unsigned short* __restrict__ Wl_t,
    const float* __restrict__ bo_s, const float* __restrict__ b1,
    const float* __restrict__ b2, float* __restrict__ out, int n)
{
  __shared__ alignas(16) unsigned short SA[96][40];    // A-operand k-tiles
  __shared__ alignas(16) unsigned short SB[256][40];   // weight k-tiles
  __shared__ alignas(16) unsigned short A1[32][264];   // x1 bf16
  __shared__ alignas(16) unsigned short A2[32][264];   // h bf16
  __shared__ float YG[32][132];                        // sigmoid gate

  const int tid = threadIdx.x;
  const int wv = tid >> 6, lane = tid & 63;
  const int l15 = lane & 15, l4 = lane >> 4;
  const int nb = blockIdx.x * 32;
  const int nb3 = nb * 3;
  const int n3 = 3 * n;

  // ---------- A1: xmid scalar ----------
  {
    f32x4 acc[2][2];
    #pragma unroll
    for (int mi = 0; mi < 2; ++mi){ acc[mi][0] = (f32x4){0,0,0,0}; acc[mi][1] = (f32x4){0,0,0,0}; }
    for (int kt = 0; kt < 4; ++kt){
      int k0 = kt * 32;
      {
        int r = tid >> 3, c4 = (tid & 7) * 4;
        int node = nb + r;
        u16x4 pk = (u16x4){0,0,0,0};
        if (node < n){
          float4 v = *(const float4*)&aggs[(size_t)node * 128 + k0 + c4];
          pk = (u16x4){f2bf(v.x), f2bf(v.y), f2bf(v.z), f2bf(v.w)};
        }
        *(u16x4*)&SA[r][c4] = pk;
      }
      for (int i = tid; i < 512; i += 256){
        int col = i >> 2, kc = (i & 3) * 8;
        *(bf16x8*)&SB[col][kc] = *(const bf16x8*)&Wos_t[(size_t)col * 128 + k0 + kc];
      }
      __syncthreads();
      bf16x8 af[2];
      af[0] = *(const bf16x8*)&SA[l15][l4 * 8];
      af[1] = *(const bf16x8*)&SA[16 + l15][l4 * 8];
      #pragma unroll
      for (int ni = 0; ni < 2; ++ni){
        bf16x8 bf = *(const bf16x8*)&SB[wv * 32 + ni * 16 + l15][l4 * 8];
        acc[0][ni] = __builtin_amdgcn_mfma_f32_16x16x32_bf16(af[0], bf, acc[0][ni], 0, 0, 0);
        acc[1][ni] = __builtin_amdgcn_mfma_f32_16x16x32_bf16(af[1], bf, acc[1][ni], 0, 0, 0);
      }
      __syncthreads();
    }
    #pragma unroll
    for (int mi = 0; mi < 2; ++mi){
      #pragma unroll
      for (int ni = 0; ni < 2; ++ni){
        int col = wv * 32 + ni * 16 + l15;
        #pragma unroll
        for (int rr = 0; rr < 4; ++rr){
          int node = nb + mi * 16 + l4 * 4 + rr;
          if (node < n){
            size_t o = (size_t)node * 512 + col;
            out[o] = acc[mi][ni][rr] + bo_s[col] + x[o];
          }
        }
      }
    }
  }
  __syncthreads();

  // ---------- A2: xmid vector (K=32, one tile) ----------
  {
    f32x4 acc[6][2];
    #pragma unroll
    for (int mi = 0; mi < 6; ++mi){ acc[mi][0] = (f32x4){0,0,0,0}; acc[mi][1] = (f32x4){0,0,0,0}; }
    for (int i = tid; i < 768; i += 256){
      int r = i >> 3, c4 = (i & 7) * 4;
      int vr = nb3 + r;
      u16x4 pk = (u16x4){0,0,0,0};
      if (vr < n3){
        float tv = t[vr];
        float4 v = *(const float4*)&aggp[(size_t)vr * 32 + c4];
        pk = (u16x4){f2bf(v.x - tv), f2bf(v.y - tv), f2bf(v.z - tv), f2bf(v.w - tv)};
      }
      *(u16x4*)&SA[r][c4] = pk;
    }
    for (int i = tid; i < 512; i += 256){
      int col = i >> 2, kc = (i & 3) * 8;
      *(bf16x8*)&SB[col][kc] = *(const bf16x8*)&Wop_t[(size_t)col * 32 + kc];
    }
    __syncthreads();
    bf16x8 af[6];
    #pragma unroll
    for (int mi = 0; mi < 6; ++mi) af[mi] = *(const bf16x8*)&SA[mi * 16 + l15][l4 * 8];
    #pragma unroll
    for (int ni = 0; ni < 2; ++ni){
      bf16x8 bf = *(const bf16x8*)&SB[wv * 32 + ni * 16 + l15][l4 * 8];
      #pragma unroll
      for (int mi = 0; mi < 6; ++mi)
        acc[mi][ni] = __builtin_amdgcn_mfma_f32_16x16x32_bf16(af[mi], bf, acc[mi][ni], 0, 0, 0);
    }
    __syncthreads();
    #pragma unroll
    for (int mi = 0; mi < 6; ++mi){
      #pragma unroll
      for (int ni = 0; ni < 2; ++ni){
        int col = wv * 32 + ni * 16 + l15;
        #pragma unroll
        for (int rr = 0; rr < 4; ++rr){
          int r = mi * 16 + l4 * 4 + rr;
          int vr = nb3 + r;
          if (vr < n3){
            int nl = r / 3, d = r - nl * 3;
            size_t o = (size_t)(nb + nl) * 512 + (size_t)(d + 1) * 128 + col;
            out[o] = acc[mi][ni][rr] + x[o];
          }
        }
      }
    }
  }
  __syncthreads();

  // ---------- B: x1 -> A1 ----------
  for (int i = tid; i < 32 * 128; i += 256){
    int r = i >> 7, c = i & 127;
    int node = nb + r;
    if (node < n){
      const float* b = out + (size_t)node * 512;
      A1[r][c] = f2bf(b[c]);
      float v1 = b[128 + c], v2 = b[256 + c], v3 = b[384 + c];
      A1[r][128 + c] = f2bf(sqrtf(v1*v1 + v2*v2 + v3*v3 + 1e-4f));
    } else { A1[r][c] = 0; A1[r][128 + c] = 0; }
  }
  __syncthreads();

  // ---------- C: h = gelu(x1@W1 + b1) -> A2 ----------
  {
    f32x4 acc[2][4];
    #pragma unroll
    for (int mi = 0; mi < 2; ++mi)
      #pragma unroll
      for (int ni = 0; ni < 4; ++ni) acc[mi][ni] = (f32x4){0,0,0,0};
    for (int kt = 0; kt < 8; ++kt){
      int k0 = kt * 32;
      for (int i = tid; i < 1024; i += 256){
        int col = i >> 2, kc = (i & 3) * 8;
        *(bf16x8*)&SB[col][kc] = *(const bf16x8*)&W1_t[(size_t)col * 256 + k0 + kc];
      }
      __syncthreads();
      bf16x8 af[2];
      af[0] = *(const bf16x8*)&A1[l15][k0 + l4 * 8];
      af[1] = *(const bf16x8*)&A1[16 + l15][k0 + l4 * 8];
      #pragma unroll
      for (int ni = 0; ni < 4; ++ni){
        bf16x8 bf = *(const bf16x8*)&SB[wv * 64 + ni * 16 + l15][l4 * 8];
        acc[0][ni] = __builtin_amdgcn_mfma_f32_16x16x32_bf16(af[0], bf, acc[0][ni], 0, 0, 0);
        acc[1][ni] = __builtin_amdgcn_mfma_f32_16x16x32_bf16(af[1], bf, acc[1][ni], 0, 0, 0);
      }
      __syncthreads();
    }
    #pragma unroll
    for (int mi = 0; mi < 2; ++mi){
      #pragma unroll
      for (int ni = 0; ni < 4; ++ni){
        int col = wv * 64 + ni * 16 + l15;
        #pragma unroll
        for (int rr = 0; rr < 4; ++rr){
          int row = mi * 16 + l4 * 4 + rr;
          A2[row][col] = f2bf(gelu_exact(acc[mi][ni][rr] + b1[col]));
        }
      }
    }
  }
  __syncthreads();

  // ---------- D: y = h@W2 + b2 ; scalar-out + gate ----------
  {
    f32x4 acc[2][4];
    #pragma unroll
    for (int mi = 0; mi < 2; ++mi)
      #pragma unroll
      for (int ni = 0; ni < 4; ++ni) acc[mi][ni] = (f32x4){0,0,0,0};
    for (int kt = 0; kt < 8; ++kt){
      int k0 = kt * 32;
      for (int i = tid; i < 1024; i += 256){
        int col = i >> 2, kc = (i & 3) * 8;
        *(bf16x8*)&SB[col][kc] = *(const bf16x8*)&W2_t[(size_t)col * 256 + k0 + kc];
      }
      __syncthreads();
      bf16x8 af[2];
      af[0] = *(const bf16x8*)&A2[l15][k0 + l4 * 8];
      af[1] = *(const bf16x8*)&A2[16 + l15][k0 + l4 * 8];
      #pragma unroll
      for (int ni = 0; ni < 4; ++ni){
        bf16x8 bf = *(const bf16x8*)&SB[wv * 64 + ni * 16 + l15][l4 * 8];
        acc[0][ni] = __builtin_amdgcn_mfma_f32_16x16x32_bf16(af[0], bf, acc[0][ni], 0, 0, 0);
        acc[1][ni] = __builtin_amdgcn_mfma_f32_16x16x32_bf16(af[1], bf, acc[1][ni], 0, 0, 0);
      }
      __syncthreads();
    }
    #pragma unroll
    for (int mi = 0; mi < 2; ++mi){
      #pragma unroll
      for (int ni = 0; ni < 4; ++ni){
        int col = wv * 64 + ni * 16 + l15;
        #pragma unroll
        for (int rr = 0; rr < 4; ++rr){
          int row = mi * 16 + l4 * 4 + rr;
          int node = nb + row;
          if (node >= n) continue;
          float val = acc[mi][ni][rr] + b2[col];
          if (col < 128){
            size_t o = (size_t)node * 512 + col;
            out[o] = out[o] + val;
          } else {
            YG[row][col - 128] = 1.f / (1.f + expf(-val));
          }
        }
      }
    }
  }
  __syncthreads();

  // ---------- E: out_v += (xmid_v @ Wl) * gate ----------
  {
    f32x4 acc[6][2];
    #pragma unroll
    for (int mi = 0; mi < 6; ++mi){ acc[mi][0] = (f32x4){0,0,0,0}; acc[mi][1] = (f32x4){0,0,0,0}; }
    for (int kt = 0; kt < 4; ++kt){
      int k0 = kt * 32;
      for (int i = tid; i < 768; i += 256){
        int r = i >> 3, c4 = (i & 7) * 4;
        int vr = nb3 + r;
        u16x4 pk = (u16x4){0,0,0,0};
        if (vr < n3){
          int nl = r / 3, d = r - nl * 3;
          size_t o = (size_t)(nb + nl) * 512 + (size_t)(d + 1) * 128 + k0 + c4;
          float4 v = *(const float4*)&out[o];
          pk = (u16x4){f2bf(v.x), f2bf(v.y), f2bf(v.z), f2bf(v.w)};
        }
        *(u16x4*)&SA[r][c4] = pk;
      }
      for (int i = tid; i < 512; i += 256){
        int col = i >> 2, kc = (i & 3) * 8;
        *(bf16x8*)&SB[col][kc] = *(const bf16x8*)&Wl_t[(size_t)col * 128 + k0 + kc];
      }
      __syncthreads();
      bf16x8 af[6];
      #pragma unroll
      for (int mi = 0; mi < 6; ++mi) af[mi] = *(const bf16x8*)&SA[mi * 16 + l15][l4 * 8];
      #pragma unroll
      for (int ni = 0; ni < 2; ++ni){
        bf16x8 bf = *(const bf16x8*)&SB[wv * 32 + ni * 16 + l15][l4 * 8];
        #pragma unroll
        for (int mi = 0; mi < 6; ++mi)
          acc[mi][ni] = __builtin_amdgcn_mfma_f32_16x16x32_bf16(af[mi], bf, acc[mi][ni], 0, 0, 0);
      }
      __syncthreads();
    }
    #pragma unroll
    for (int mi = 0; mi < 6; ++mi){
      #pragma unroll
      for (int ni = 0; ni < 2; ++ni){
        int col = wv * 32 + ni * 16 + l15;
        #pragma unroll
        for (int rr = 0; rr < 4; ++rr){
          int r = mi * 16 + l4 * 4 + rr;
          int vr = nb3 + r;
          if (vr < n3){
            int nl = r / 3, d = r - nl * 3;
            size_t o = (size_t)(nb + nl) * 512 + (size_t)(d + 1) * 128 + col;
            out[o] = out[o] + acc[mi][ni][rr] * YG[nl][col];
          }
        }
      }
    }
  }
}

// ---------------- launch ----------------
extern "C" void kernel_launch(void* const* d_in, const int* in_sizes, int n_in,
                              void* d_out, int out_size, void* d_ws, size_t ws_size,
                              hipStream_t stream)
{
  const float* x      = (const float*)d_in[0];
  const int*   ei     = (const int*)d_in[1];
  const float* t      = (const float*)d_in[2];
  const float* Wq     = (const float*)d_in[3];
  const float* Wk     = (const float*)d_in[4];
  const float* Wv     = (const float*)d_in[5];
  const float* Wq_pts = (const float*)d_in[6];
  const float* Wk_pts = (const float*)d_in[7];
  const float* Wv_pts = (const float*)d_in[8];
  const float* gamma  = (const float*)d_in[9];
  const float* Wo_s   = (const float*)d_in[10];
  const float* bo_s   = (const float*)d_in[11];
  const float* Wo_pts = (const float*)d_in[12];
  const float* W1     = (const float*)d_in[13];
  const float* b1     = (const float*)d_in[14];
  const float* W2     = (const float*)d_in[15];
  const float* b2     = (const float*)d_in[16];
  const float* Wl     = (const float*)d_in[17];
  float* out = (float*)d_out;

  const int n = in_sizes[0] / 512;
  const int E = in_sizes[1] / 2;

  char* wsb = (char*)d_ws;
  unsigned short* qkv_bf = (unsigned short*)(wsb);                    // [n][384] bf16
  unsigned short* pts_bf = (unsigned short*)(wsb + (size_t)n * 768);  // [3n][96] bf16
  float* aggs  = (float*)(wsb + (size_t)n * 1344);                    // [n][128] f32
  float* aggp  = (float*)(wsb + (size_t)n * 1856);                    // [3n][32] f32
  int*   deg       = (int*)(wsb + (size_t)n * 2240);
  int*   cursor    = deg + n;
  int*   row_start = cursor + n;
  int*   csr_src   = row_start + (n + 1);
  size_t int_end = (size_t)n * 2240 + (size_t)(3 * n + 1 + E) * 4;
  int_end = (int_end + 15) / 16 * 16;
  unsigned short* wbf    = (unsigned short*)(wsb + int_end);
  unsigned short* Bqkv_t = wbf;            // [384][128]
  unsigned short* Bpts_t = wbf + 49152;    // [96][128]
  unsigned short* Wos_t  = wbf + 61440;    // [128][128]
  unsigned short* Wop_t  = wbf + 77824;    // [128][32]
  unsigned short* W1_t   = wbf + 81920;    // [256][256]
  unsigned short* W2_t   = wbf + 147456;   // [256][256]
  unsigned short* Wl_t   = wbf + 212992;   // [128][128]

  // CSR build + weight pack
  hipMemsetAsync(deg, 0, sizeof(int) * (size_t)(2 * n), stream);
  count_kernel<<<(E + 255) / 256, 256, 0, stream>>>(ei, deg, E);
  pack_bf16_kernel<<<896, 256, 0, stream>>>(Wq, Wk, Wv, Wq_pts, Wk_pts, Wv_pts,
                                            Wo_s, Wo_pts, W1, W2, Wl, wbf);
  scan_kernel<<<1, 1024, 0, stream>>>(deg, row_start, n);
  fill_kernel<<<(E + 255) / 256, 256, 0, stream>>>(ei, row_start, cursor, csr_src, E);

  // s-projection: [n,128] @ [128,384] -> qkv (bf16)
  {
    dim3 grid((n + 63) / 64, 6);
    mfma_gemm<64,64,64><<<grid, 256, 0, stream>>>(
        x, 0, 512, Bqkv_t, qkv_bf, 384, nullptr, n, 128, 384, 0);
  }
  // pts-projection: [3n,128] @ [128,96] + t -> pts (bf16)
  {
    dim3 grid((3 * n + 63) / 64, 2);
    mfma_gemm<64,64,64><<<grid, 256, 0, stream>>>(
        x, 1, 0, Bpts_t, pts_bf, 96, t, 3 * n, 128, 96, 1);
  }

  // attention (one wave per node)
  attn_kernel<<<n, 64, 0, stream>>>(qkv_bf, pts_bf, gamma, row_start, csr_src,
                                    aggs, aggp, n);

  // fused tail v2 (32 nodes/block)
  fused_tail_kernel<<<(n + 31) / 32, 256, 0, stream>>>(
      aggs, aggp, t, x, Wos_t, Wop_t, W1_t, W2_t, Wl_t, bo_s, b1, b2, out, n);
}

// Round 9
// 266.816 us; speedup vs baseline: 1.1133x; 1.1133x over previous
//
#include <hip/hip_runtime.h>
#include <math.h>

#define C_DIM 128
#define H_NUM 8
#define DH_NUM 16
#define HD 128   // H*DH
#define PC 32    // H*NP

typedef __attribute__((ext_vector_type(8))) short bf16x8;
typedef __attribute__((ext_vector_type(4))) float f32x4;
typedef __attribute__((ext_vector_type(4))) unsigned short u16x4;

// ---------------- helpers ----------------
__device__ __forceinline__ float dot4f(float4 a, float4 b){
  return a.x*b.x + a.y*b.y + a.z*b.z + a.w*b.w;
}
__device__ __forceinline__ float4 scale4(float4 a, float s){
  return make_float4(a.x*s, a.y*s, a.z*s, a.w*s);
}
__device__ __forceinline__ float4 fma4(float4 acc, float p, float4 v){
  return make_float4(acc.x + p*v.x, acc.y + p*v.y, acc.z + p*v.z, acc.w + p*v.w);
}
__device__ __forceinline__ float sqdiff4(float4 a, float4 b){
  float dx = a.x - b.x, dy = a.y - b.y, dz = a.z - b.z, dw = a.w - b.w;
  return dx*dx + dy*dy + dz*dz + dw*dw;
}
__device__ __forceinline__ float gelu_exact(float v){
  return 0.5f * v * (1.0f + erff(v * 0.70710678118654752440f));
}
__device__ __forceinline__ unsigned short f2bf(float f){
  unsigned u = __builtin_bit_cast(unsigned, f);
  u += 0x7FFF + ((u >> 16) & 1);           // RNE to bf16
  return (unsigned short)(u >> 16);
}
__device__ __forceinline__ void ldbf8(const unsigned short* p, float4& lo, float4& hi){
  uint4 u = *(const uint4*)p;
  lo.x = __uint_as_float(u.x << 16); lo.y = __uint_as_float(u.x & 0xffff0000u);
  lo.z = __uint_as_float(u.y << 16); lo.w = __uint_as_float(u.y & 0xffff0000u);
  hi.x = __uint_as_float(u.z << 16); hi.y = __uint_as_float(u.z & 0xffff0000u);
  hi.z = __uint_as_float(u.w << 16); hi.w = __uint_as_float(u.w & 0xffff0000u);
}
__device__ __forceinline__ float4 ldbf4(const unsigned short* p){
  uint2 u = *(const uint2*)p;
  return make_float4(__uint_as_float(u.x << 16), __uint_as_float(u.x & 0xffff0000u),
                     __uint_as_float(u.y << 16), __uint_as_float(u.y & 0xffff0000u));
}
// row-offset modes: 0 -> r*ld ; 1 -> x-like (N,4,C) vector rows
__device__ __forceinline__ size_t row_off(int mode, int r, int ld){
  if (mode == 0) return (size_t)r * (size_t)ld;
  int n3 = r / 3;
  int xd = r - n3 * 3;
  return (size_t)n3 * 512 + (size_t)(xd + 1) * 128;
}

#define RED4(v, off) { v.x += __shfl_xor(v.x, off); v.y += __shfl_xor(v.y, off); \
                       v.z += __shfl_xor(v.z, off); v.w += __shfl_xor(v.w, off); }

// ---------------- CSR build ----------------
__global__ void count_kernel(const int* __restrict__ ei, int* __restrict__ deg, int E){
  int e = blockIdx.x * blockDim.x + threadIdx.x;
  if (e < E) atomicAdd(&deg[ei[E + e]], 1);
}

__global__ __launch_bounds__(1024) void scan_kernel(const int* __restrict__ deg,
                                                    int* __restrict__ row_start, int n){
  __shared__ int sums[1024];
  int tid = threadIdx.x;
  int chunk = (n + 1023) >> 10;
  int beg = tid * chunk;
  int end = beg + chunk; if (end > n) end = n;
  int s = 0;
  for (int i = beg; i < end; ++i) s += deg[i];
  sums[tid] = s;
  __syncthreads();
  for (int off = 1; off < 1024; off <<= 1){
    int v = (tid >= off) ? sums[tid - off] : 0;
    __syncthreads();
    sums[tid] += v;
    __syncthreads();
  }
  int run = (tid > 0) ? sums[tid - 1] : 0;
  for (int i = beg; i < end; ++i){ row_start[i] = run; run += deg[i]; }
  if (tid == 1023) row_start[n] = sums[1023];
}

__global__ void fill_kernel(const int* __restrict__ ei, const int* __restrict__ row_start,
                            int* __restrict__ cursor, int* __restrict__ csr_src, int E){
  int e = blockIdx.x * blockDim.x + threadIdx.x;
  if (e >= E) return;
  int s = ei[e];
  int d = ei[E + e];
  int pos = atomicAdd(&cursor[d], 1);
  csr_src[row_start[d] + pos] = s;
}

// ------- pack ALL weights to bf16, transposed [N][K], concatenated -------
__global__ void pack_bf16_kernel(const float* __restrict__ Wq, const float* __restrict__ Wk,
    const float* __restrict__ Wv, const float* __restrict__ Wqp,
    const float* __restrict__ Wkp, const float* __restrict__ Wvp,
    const float* __restrict__ Wo_s, const float* __restrict__ Wo_pts,
    const float* __restrict__ W1, const float* __restrict__ W2,
    const float* __restrict__ Wl, unsigned short* __restrict__ out)
{
  int i = blockIdx.x * blockDim.x + threadIdx.x;
  float v;
  if (i < 49152){                       // Bqkv_t [384][128]
    int nn = i >> 7, k = i & 127;
    int sel = nn >> 7, nc = nn & 127;
    const float* W = (sel == 0) ? Wq : (sel == 1) ? Wk : Wv;
    v = W[k * 128 + nc];
  } else if (i < 61440){                // Bpts_t [96][128]
    int j = i - 49152;
    int nn = j >> 7, k = j & 127;
    int sel = nn >> 5, nc = nn & 31;
    const float* W = (sel == 0) ? Wqp : (sel == 1) ? Wkp : Wvp;
    v = W[k * 32 + nc];
  } else if (i < 77824){                // Wos_t [128][128]
    int j = i - 61440;
    int nn = j >> 7, k = j & 127;
    v = Wo_s[k * 128 + nn];
  } else if (i < 81920){                // Wop_t [128][32]
    int j = i - 77824;
    int nn = j >> 5, k = j & 31;
    v = Wo_pts[k * 128 + nn];
  } else if (i < 147456){               // W1_t [256][256]
    int j = i - 81920;
    int nn = j >> 8, k = j & 255;
    v = W1[k * 256 + nn];
  } else if (i < 212992){               // W2_t [256][256]
    int j = i - 147456;
    int nn = j >> 8, k = j & 255;
    v = W2[k * 256 + nn];
  } else {                              // Wl_t [128][128]
    int j = i - 212992;
    int nn = j >> 7, k = j & 127;
    v = Wl[k * 128 + nn];
  }
  out[i] = f2bf(v);
}

// ------- combined projection: one dispatch for qkv (y<6) and pts (y>=6) -----
// y<6 : qkv col-block y    : [n,128]@[128,384] -> qkv_bf (bf16)
// y>=6: pts col-block y-6  : [3n,128]@[128,96] + t -> pts_bf (bf16)
__global__ __launch_bounds__(256) void proj_kernel(
    const float* __restrict__ x, const float* __restrict__ t,
    const unsigned short* __restrict__ Bqkv_t, const unsigned short* __restrict__ Bpts_t,
    unsigned short* __restrict__ qkv_bf, unsigned short* __restrict__ pts_bf, int n)
{
  constexpr int BM = 64, BN = 64, BK = 64, LDSK = 72;
  __shared__ alignas(16) unsigned short As[BM][LDSK];
  __shared__ alignas(16) unsigned short Bs[BN][LDSK];
  const int job = blockIdx.y;
  const bool isS = (job < 6);
  const unsigned short* Bt = isS ? Bqkv_t : Bpts_t;
  unsigned short* Cb = isS ? qkv_bf : pts_bf;
  const int amode = isS ? 0 : 1;
  const int M  = isS ? n : 3 * n;
  const int Nc = isS ? 384 : 96;
  const int cb = (isS ? job : job - 6) * 64;
  const int rb = blockIdx.x * BM;
  if (rb >= M || cb >= Nc) return;

  const int tid = threadIdx.x;
  const int wave = tid >> 6;
  const int lane = tid & 63;
  const int wr = wave >> 1;
  const int wc = wave & 1;
  const int l15 = lane & 15;
  const int l4  = lane >> 4;

  f32x4 acc[2][2];
  #pragma unroll
  for (int mi = 0; mi < 2; ++mi){ acc[mi][0] = (f32x4){0,0,0,0}; acc[mi][1] = (f32x4){0,0,0,0}; }

  for (int k0 = 0; k0 < 128; k0 += BK){
    // stage A: fp32 -> bf16
    #pragma unroll
    for (int i = 0; i < 4; ++i){
      int fi = tid + i * 256;
      int r  = fi >> 4;           // 16 float4 per row (BK=64)
      int c4 = (fi & 15) * 4;
      int row = rb + r;
      u16x4 pk = (u16x4){0,0,0,0};
      if (row < M){
        float4 v = *(const float4*)&x[row_off(amode, row, 512) + (size_t)(k0 + c4)];
        pk = (u16x4){f2bf(v.x), f2bf(v.y), f2bf(v.z), f2bf(v.w)};
      }
      *(u16x4*)&As[r][c4] = pk;
    }
    // stage B (pre-transposed bf16)
    #pragma unroll
    for (int i = 0; i < 2; ++i){
      int fi = tid + i * 256;
      int r  = fi >> 3;
      int kc = (fi & 7) * 8;
      int col = cb + r;
      bf16x8 val = 0;
      if (col < Nc) val = *(const bf16x8*)&Bt[(size_t)col * 128 + k0 + kc];
      *(bf16x8*)&Bs[r][kc] = val;
    }
    __syncthreads();
    #pragma unroll
    for (int kk = 0; kk < 2; ++kk){
      bf16x8 af[2], bfr[2];
      #pragma unroll
      for (int mi = 0; mi < 2; ++mi)
        af[mi] = *(const bf16x8*)&As[wr * 32 + mi * 16 + l15][kk * 32 + l4 * 8];
      #pragma unroll
      for (int ni = 0; ni < 2; ++ni)
        bfr[ni] = *(const bf16x8*)&Bs[wc * 32 + ni * 16 + l15][kk * 32 + l4 * 8];
      #pragma unroll
      for (int mi = 0; mi < 2; ++mi)
        #pragma unroll
        for (int ni = 0; ni < 2; ++ni)
          acc[mi][ni] = __builtin_amdgcn_mfma_f32_16x16x32_bf16(
              af[mi], bfr[ni], acc[mi][ni], 0, 0, 0);
    }
    __syncthreads();
  }

  #pragma unroll
  for (int mi = 0; mi < 2; ++mi){
    #pragma unroll
    for (int ni = 0; ni < 2; ++ni){
      int col = cb + wc * 32 + ni * 16 + l15;
      if (col >= Nc) continue;
      #pragma unroll
      for (int r = 0; r < 4; ++r){
        int row = rb + wr * 32 + mi * 16 + l4 * 4 + r;
        if (row >= M) continue;
        float val = acc[mi][ni][r];
        if (!isS) val += t[row];
        Cb[(size_t)row * Nc + col] = f2bf(val);
      }
    }
  }
}

// ---------------- per-node online-softmax attention over CSR (bf16 in) -----
__global__ __launch_bounds__(64) void attn_kernel(
    const unsigned short* __restrict__ qkv, const unsigned short* __restrict__ pts,
    const float* __restrict__ gamma,
    const int* __restrict__ row_start, const int* __restrict__ csr_src,
    float* __restrict__ agg_s, float* __restrict__ agg_p, int n)
{
  const int node = blockIdx.x;
  if (node >= n) return;
  const int lane = threadIdx.x;
  const int g = lane >> 3;
  const int h = lane & 7;

  float4 qa, qb, qc, qd;
  ldbf8(qkv + (size_t)node * 384 + h * 16, qa, qb);
  ldbf8(qkv + (size_t)node * 384 + h * 16 + 8, qc, qd);
  const float4 qp0 = ldbf4(pts + ((size_t)node * 3 + 0) * 96 + h * 4);
  const float4 qp1 = ldbf4(pts + ((size_t)node * 3 + 1) * 96 + h * 4);
  const float4 qp2 = ldbf4(pts + ((size_t)node * 3 + 2) * 96 + h * 4);
  const float c05 = 0.5f * log1pf(expf(gamma[h]));

  const int e0 = row_start[node], e1 = row_start[node + 1];

  float m_run = -INFINITY;
  float zacc = 0.f;
  float4 as0 = make_float4(0,0,0,0), as1 = as0, as2 = as0, as3 = as0;
  float4 ap0 = as0, ap1 = as0, ap2 = as0;

  for (int base = e0; base < e1; base += 8){
    const int e = base + g;
    const bool valid = (e < e1);
    const int src = valid ? csr_src[e] : 0;

    float4 ka, kb, kc2, kd;
    ldbf8(qkv + (size_t)src * 384 + 128 + h * 16, ka, kb);
    ldbf8(qkv + (size_t)src * 384 + 128 + h * 16 + 8, kc2, kd);
    float dot = dot4f(qa, ka) + dot4f(qb, kb) + dot4f(qc, kc2) + dot4f(qd, kd);
    const float4 kp0 = ldbf4(pts + ((size_t)src * 3 + 0) * 96 + 32 + h * 4);
    const float4 kp1 = ldbf4(pts + ((size_t)src * 3 + 1) * 96 + 32 + h * 4);
    const float4 kp2 = ldbf4(pts + ((size_t)src * 3 + 2) * 96 + 32 + h * 4);
    float pd = sqdiff4(qp0, kp0) + sqdiff4(qp1, kp1) + sqdiff4(qp2, kp2);
    float logit = valid ? (dot * 0.25f - c05 * pd) : -INFINITY;

    float tmax = logit;
    tmax = fmaxf(tmax, __shfl_xor(tmax, 8));
    tmax = fmaxf(tmax, __shfl_xor(tmax, 16));
    tmax = fmaxf(tmax, __shfl_xor(tmax, 32));
    float m_new = fmaxf(m_run, tmax);
    float sc = expf(m_run - m_new);
    float pe = valid ? expf(logit - m_new) : 0.f;
    m_run = m_new;

    float4 vv0, vv1, vv2, vv3;
    ldbf8(qkv + (size_t)src * 384 + 256 + h * 16, vv0, vv1);
    ldbf8(qkv + (size_t)src * 384 + 256 + h * 16 + 8, vv2, vv3);
    const float4 vp0 = ldbf4(pts + ((size_t)src * 3 + 0) * 96 + 64 + h * 4);
    const float4 vp1 = ldbf4(pts + ((size_t)src * 3 + 1) * 96 + 64 + h * 4);
    const float4 vp2 = ldbf4(pts + ((size_t)src * 3 + 2) * 96 + 64 + h * 4);

    zacc = zacc * sc + pe;
    as0 = fma4(scale4(as0, sc), pe, vv0);
    as1 = fma4(scale4(as1, sc), pe, vv1);
    as2 = fma4(scale4(as2, sc), pe, vv2);
    as3 = fma4(scale4(as3, sc), pe, vv3);
    ap0 = fma4(scale4(ap0, sc), pe, vp0);
    ap1 = fma4(scale4(ap1, sc), pe, vp1);
    ap2 = fma4(scale4(ap2, sc), pe, vp2);
  }

  for (int off = 8; off < 64; off <<= 1){
    zacc += __shfl_xor(zacc, off);
    RED4(as0, off); RED4(as1, off); RED4(as2, off); RED4(as3, off);
    RED4(ap0, off); RED4(ap1, off); RED4(ap2, off);
  }
  float inv = 1.f / (zacc + 1e-9f);
  if (g == 0){
    float4* o = (float4*)(agg_s + (size_t)node * HD + h * DH_NUM);
    o[0] = scale4(as0, inv); o[1] = scale4(as1, inv);
    o[2] = scale4(as2, inv); o[3] = scale4(as3, inv);
    *(float4*)(agg_p + ((size_t)node * 3 + 0) * PC + h * 4) = scale4(ap0, inv);
    *(float4*)(agg_p + ((size_t)node * 3 + 1) * PC + h * 4) = scale4(ap1, inv);
    *(float4*)(agg_p + ((size_t)node * 3 + 2) * PC + h * 4) = scale4(ap2, inv);
  }
}

// ============ fused tail: 16 nodes/block (R7-measured best) ============
__global__ __launch_bounds__(256) void fused_tail_kernel(
    const float* __restrict__ aggs, const float* __restrict__ aggp,
    const float* __restrict__ t, const float* __restrict__ x,
    const unsigned short* __restrict__ Wos_t, const unsigned short* __restrict__ Wop_t,
    const unsigned short* __restrict__ W1_t, const unsigned short* __restrict__ W2_t,
    const unsigned short* __restrict__ Wl_t,
    const float* __restrict__ bo_s, const float* __restrict__ b1,
    const float* __restrict__ b2, float* __restrict__ out, int n)
{
  __shared__ alignas(16) unsigned short SA[48][40];    // A-stage
  __shared__ alignas(16) unsigned short SB[256][40];   // weight k-tiles
  __shared__ alignas(16) unsigned short A1[16][264];   // x1 bf16
  __shared__ alignas(16) unsigned short A2[16][264];   // h bf16
  __shared__ float YG[16][128];                        // sigmoid gate

  const int tid = threadIdx.x;
  const int wv = tid >> 6, lane = tid & 63;
  const int l15 = lane & 15, l4 = lane >> 4;
  const int nb = blockIdx.x * 16;
  const int nb3 = nb * 3;

  // ---------- A1: xmid scalar ----------
  {
    f32x4 acc[2] = {{0,0,0,0},{0,0,0,0}};
    for (int k0 = 0; k0 < 128; k0 += 32){
      for (int i = tid; i < 16 * 8; i += 256){
        int r = i >> 3, c4 = (i & 7) * 4;
        int node = nb + r;
        u16x4 pk = (u16x4){0,0,0,0};
        if (node < n){
          float4 v = *(const float4*)&aggs[(size_t)node * 128 + k0 + c4];
          pk = (u16x4){f2bf(v.x), f2bf(v.y), f2bf(v.z), f2bf(v.w)};
        }
        *(u16x4*)&SA[r][c4] = pk;
      }
      for (int i = tid; i < 128 * 4; i += 256){
        int col = i >> 2, kc = (i & 3) * 8;
        *(bf16x8*)&SB[col][kc] = *(const bf16x8*)&Wos_t[(size_t)col * 128 + k0 + kc];
      }
      __syncthreads();
      bf16x8 af = *(const bf16x8*)&SA[l15][l4 * 8];
      #pragma unroll
      for (int ni = 0; ni < 2; ++ni){
        bf16x8 bf = *(const bf16x8*)&SB[wv * 32 + ni * 16 + l15][l4 * 8];
        acc[ni] = __builtin_amdgcn_mfma_f32_16x16x32_bf16(af, bf, acc[ni], 0, 0, 0);
      }
      __syncthreads();
    }
    #pragma unroll
    for (int ni = 0; ni < 2; ++ni){
      int col = wv * 32 + ni * 16 + l15;
      #pragma unroll
      for (int rr = 0; rr < 4; ++rr){
        int node = nb + l4 * 4 + rr;
        if (node < n){
          size_t o = (size_t)node * 512 + col;
          out[o] = acc[ni][rr] + bo_s[col] + x[o];
        }
      }
    }
  }
  __syncthreads();

  // ---------- A2: xmid vector ----------
  {
    f32x4 acc[3][2];
    #pragma unroll
    for (int mi = 0; mi < 3; ++mi){ acc[mi][0] = (f32x4){0,0,0,0}; acc[mi][1] = (f32x4){0,0,0,0}; }
    for (int i = tid; i < 48 * 8; i += 256){
      int r = i >> 3, c4 = (i & 7) * 4;
      int vr = nb3 + r;
      u16x4 pk = (u16x4){0,0,0,0};
      if (vr < 3 * n){
        float tv = t[vr];
        float4 v = *(const float4*)&aggp[(size_t)vr * 32 + c4];
        pk = (u16x4){f2bf(v.x - tv), f2bf(v.y - tv), f2bf(v.z - tv), f2bf(v.w - tv)};
      }
      *(u16x4*)&SA[r][c4] = pk;
    }
    for (int i = tid; i < 128 * 4; i += 256){
      int col = i >> 2, kc = (i & 3) * 8;
      *(bf16x8*)&SB[col][kc] = *(const bf16x8*)&Wop_t[(size_t)col * 32 + kc];
    }
    __syncthreads();
    bf16x8 af[3];
    #pragma unroll
    for (int mi = 0; mi < 3; ++mi) af[mi] = *(const bf16x8*)&SA[mi * 16 + l15][l4 * 8];
    #pragma unroll
    for (int ni = 0; ni < 2; ++ni){
      bf16x8 bf = *(const bf16x8*)&SB[wv * 32 + ni * 16 + l15][l4 * 8];
      #pragma unroll
      for (int mi = 0; mi < 3; ++mi)
        acc[mi][ni] = __builtin_amdgcn_mfma_f32_16x16x32_bf16(af[mi], bf, acc[mi][ni], 0, 0, 0);
    }
    __syncthreads();
    #pragma unroll
    for (int mi = 0; mi < 3; ++mi){
      #pragma unroll
      for (int ni = 0; ni < 2; ++ni){
        int col = wv * 32 + ni * 16 + l15;
        #pragma unroll
        for (int rr = 0; rr < 4; ++rr){
          int r = mi * 16 + l4 * 4 + rr;
          int vr = nb3 + r;
          if (vr < 3 * n){
            int nl = r / 3, d = r - nl * 3;
            size_t o = (size_t)(nb + nl) * 512 + (size_t)(d + 1) * 128 + col;
            out[o] = acc[mi][ni][rr] + x[o];
          }
        }
      }
    }
  }
  __syncthreads();

  // ---------- B: x1 -> A1 ----------
  for (int i = tid; i < 16 * 128; i += 256){
    int r = i >> 7, c = i & 127;
    int node = nb + r;
    if (node < n){
      const float* b = out + (size_t)node * 512;
      A1[r][c] = f2bf(b[c]);
      float v1 = b[128 + c], v2 = b[256 + c], v3 = b[384 + c];
      A1[r][128 + c] = f2bf(sqrtf(v1*v1 + v2*v2 + v3*v3 + 1e-4f));
    } else { A1[r][c] = 0; A1[r][128 + c] = 0; }
  }
  __syncthreads();

  // ---------- C: h = gelu(x1@W1 + b1) -> A2 ----------
  {
    f32x4 acc[4] = {{0,0,0,0},{0,0,0,0},{0,0,0,0},{0,0,0,0}};
    for (int k0 = 0; k0 < 256; k0 += 32){
      for (int i = tid; i < 256 * 4; i += 256){
        int col = i >> 2, kc = (i & 3) * 8;
        *(bf16x8*)&SB[col][kc] = *(const bf16x8*)&W1_t[(size_t)col * 256 + k0 + kc];
      }
      __syncthreads();
      bf16x8 af = *(const bf16x8*)&A1[l15][k0 + l4 * 8];
      #pragma unroll
      for (int ni = 0; ni < 4; ++ni){
        bf16x8 bf = *(const bf16x8*)&SB[wv * 64 + ni * 16 + l15][l4 * 8];
        acc[ni] = __builtin_amdgcn_mfma_f32_16x16x32_bf16(af, bf, acc[ni], 0, 0, 0);
      }
      __syncthreads();
    }
    #pragma unroll
    for (int ni = 0; ni < 4; ++ni){
      int col = wv * 64 + ni * 16 + l15;
      #pragma unroll
      for (int rr = 0; rr < 4; ++rr){
        int row = l4 * 4 + rr;
        A2[row][col] = f2bf(gelu_exact(acc[ni][rr] + b1[col]));
      }
    }
  }
  __syncthreads();

  // ---------- D: y = h@W2 + b2 ; scalar-out + gate ----------
  {
    f32x4 acc[4] = {{0,0,0,0},{0,0,0,0},{0,0,0,0},{0,0,0,0}};
    for (int k0 = 0; k0 < 256; k0 += 32){
      for (int i = tid; i < 256 * 4; i += 256){
        int col = i >> 2, kc = (i & 3) * 8;
        *(bf16x8*)&SB[col][kc] = *(const bf16x8*)&W2_t[(size_t)col * 256 + k0 + kc];
      }
      __syncthreads();
      bf16x8 af = *(const bf16x8*)&A2[l15][k0 + l4 * 8];
      #pragma unroll
      for (int ni = 0; ni < 4; ++ni){
        bf16x8 bf = *(const bf16x8*)&SB[wv * 64 + ni * 16 + l15][l4 * 8];
        acc[ni] = __builtin_amdgcn_mfma_f32_16x16x32_bf16(af, bf, acc[ni], 0, 0, 0);
      }
      __syncthreads();
    }
    #pragma unroll
    for (int ni = 0; ni < 4; ++ni){
      int col = wv * 64 + ni * 16 + l15;
      #pragma unroll
      for (int rr = 0; rr < 4; ++rr){
        int row = l4 * 4 + rr;
        int node = nb + row;
        if (node >= n) continue;
        float val = acc[ni][rr] + b2[col];
        if (col < 128){
          size_t o = (size_t)node * 512 + col;
          out[o] = out[o] + val;
        } else {
          YG[row][col - 128] = 1.f / (1.f + expf(-val));
        }
      }
    }
  }
  __syncthreads();

  // ---------- E: out_v += (xmid_v @ Wl) * gate ----------
  {
    f32x4 acc[3][2];
    #pragma unroll
    for (int mi = 0; mi < 3; ++mi){ acc[mi][0] = (f32x4){0,0,0,0}; acc[mi][1] = (f32x4){0,0,0,0}; }
    for (int k0 = 0; k0 < 128; k0 += 32){
      for (int i = tid; i < 48 * 8; i += 256){
        int r = i >> 3, c4 = (i & 7) * 4;
        int vr = nb3 + r;
        u16x4 pk = (u16x4){0,0,0,0};
        if (vr < 3 * n){
          int nl = r / 3, d = r - nl * 3;
          size_t o = (size_t)(nb + nl) * 512 + (size_t)(d + 1) * 128 + k0 + c4;
          float4 v = *(const float4*)&out[o];
          pk = (u16x4){f2bf(v.x), f2bf(v.y), f2bf(v.z), f2bf(v.w)};
        }
        *(u16x4*)&SA[r][c4] = pk;
      }
      for (int i = tid; i < 128 * 4; i += 256){
        int col = i >> 2, kc = (i & 3) * 8;
        *(bf16x8*)&SB[col][kc] = *(const bf16x8*)&Wl_t[(size_t)col * 128 + k0 + kc];
      }
      __syncthreads();
      bf16x8 af[3];
      #pragma unroll
      for (int mi = 0; mi < 3; ++mi) af[mi] = *(const bf16x8*)&SA[mi * 16 + l15][l4 * 8];
      #pragma unroll
      for (int ni = 0; ni < 2; ++ni){
        bf16x8 bf = *(const bf16x8*)&SB[wv * 32 + ni * 16 + l15][l4 * 8];
        #pragma unroll
        for (int mi = 0; mi < 3; ++mi)
          acc[mi][ni] = __builtin_amdgcn_mfma_f32_16x16x32_bf16(af[mi], bf, acc[mi][ni], 0, 0, 0);
      }
      __syncthreads();
    }
    #pragma unroll
    for (int mi = 0; mi < 3; ++mi){
      #pragma unroll
      for (int ni = 0; ni < 2; ++ni){
        int col = wv * 32 + ni * 16 + l15;
        #pragma unroll
        for (int rr = 0; rr < 4; ++rr){
          int r = mi * 16 + l4 * 4 + rr;
          int vr = nb3 + r;
          if (vr < 3 * n){
            int nl = r / 3, d = r - nl * 3;
            size_t o = (size_t)(nb + nl) * 512 + (size_t)(d + 1) * 128 + col;
            out[o] = out[o] + acc[mi][ni][rr] * YG[nl][col];
          }
        }
      }
    }
  }
}

// ---------------- launch ----------------
extern "C" void kernel_launch(void* const* d_in, const int* in_sizes, int n_in,
                              void* d_out, int out_size, void* d_ws, size_t ws_size,
                              hipStream_t stream)
{
  const float* x      = (const float*)d_in[0];
  const int*   ei     = (const int*)d_in[1];
  const float* t      = (const float*)d_in[2];
  const float* Wq     = (const float*)d_in[3];
  const float* Wk     = (const float*)d_in[4];
  const float* Wv     = (const float*)d_in[5];
  const float* Wq_pts = (const float*)d_in[6];
  const float* Wk_pts = (const float*)d_in[7];
  const float* Wv_pts = (const float*)d_in[8];
  const float* gamma  = (const float*)d_in[9];
  const float* Wo_s   = (const float*)d_in[10];
  const float* bo_s   = (const float*)d_in[11];
  const float* Wo_pts = (const float*)d_in[12];
  const float* W1     = (const float*)d_in[13];
  const float* b1     = (const float*)d_in[14];
  const float* W2     = (const float*)d_in[15];
  const float* b2     = (const float*)d_in[16];
  const float* Wl     = (const float*)d_in[17];
  float* out = (float*)d_out;

  const int n = in_sizes[0] / 512;
  const int E = in_sizes[1] / 2;

  char* wsb = (char*)d_ws;
  unsigned short* qkv_bf = (unsigned short*)(wsb);                    // [n][384] bf16
  unsigned short* pts_bf = (unsigned short*)(wsb + (size_t)n * 768);  // [3n][96] bf16
  float* aggs  = (float*)(wsb + (size_t)n * 1344);                    // [n][128] f32
  float* aggp  = (float*)(wsb + (size_t)n * 1856);                    // [3n][32] f32
  int*   deg       = (int*)(wsb + (size_t)n * 2240);
  int*   cursor    = deg + n;
  int*   row_start = cursor + n;
  int*   csr_src   = row_start + (n + 1);
  size_t int_end = (size_t)n * 2240 + (size_t)(3 * n + 1 + E) * 4;
  int_end = (int_end + 15) / 16 * 16;
  unsigned short* wbf    = (unsigned short*)(wsb + int_end);
  unsigned short* Bqkv_t = wbf;            // [384][128]
  unsigned short* Bpts_t = wbf + 49152;    // [96][128]
  unsigned short* Wos_t  = wbf + 61440;    // [128][128]
  unsigned short* Wop_t  = wbf + 77824;    // [128][32]
  unsigned short* W1_t   = wbf + 81920;    // [256][256]
  unsigned short* W2_t   = wbf + 147456;   // [256][256]
  unsigned short* Wl_t   = wbf + 212992;   // [128][128]

  // CSR build + weight pack
  hipMemsetAsync(deg, 0, sizeof(int) * (size_t)(2 * n), stream);
  count_kernel<<<(E + 255) / 256, 256, 0, stream>>>(ei, deg, E);
  pack_bf16_kernel<<<896, 256, 0, stream>>>(Wq, Wk, Wv, Wq_pts, Wk_pts, Wv_pts,
                                            Wo_s, Wo_pts, W1, W2, Wl, wbf);
  scan_kernel<<<1, 1024, 0, stream>>>(deg, row_start, n);
  fill_kernel<<<(E + 255) / 256, 256, 0, stream>>>(ei, row_start, cursor, csr_src, E);

  // combined projections (one dispatch)
  {
    dim3 grid((3 * n + 63) / 64, 8);
    proj_kernel<<<grid, 256, 0, stream>>>(x, t, Bqkv_t, Bpts_t, qkv_bf, pts_bf, n);
  }

  // attention (one wave per node)
  attn_kernel<<<n, 64, 0, stream>>>(qkv_bf, pts_bf, gamma, row_start, csr_src,
                                    aggs, aggp, n);

  // fused tail (16 nodes/block — measured best)
  fused_tail_kernel<<<(n + 15) / 16, 256, 0, stream>>>(
      aggs, aggp, t, x, Wos_t, Wop_t, W1_t, W2_t, Wl_t, bo_s, b1, b2, out, n);
}